// Round 9
// baseline (33.225 us; speedup 1.0000x reference)
//
#include <hip/hip_runtime.h>
#include <hip/hip_bf16.h>
#include <hip/hip_fp16.h>

#define N9 9
#define TPX 32          // pixels per block (contiguous j within one row)
#define CIN 64
#define COUT 64
#define HH 64
#define WW 64
#define BB 8
#define KTOT 576        // 9 points * 64 ci, k = n*64 + ci
#define SROW 584        // padded LDS row stride in shorts (1168 B = 73*16)
#define NTASK (N9 * TPX)

typedef short bf16x8 __attribute__((ext_vector_type(8)));
typedef float f32x4 __attribute__((ext_vector_type(4)));
typedef float f32x2 __attribute__((ext_vector_type(2)));
typedef unsigned int uint32x4 __attribute__((ext_vector_type(4)));

__device__ __forceinline__ float uasf(unsigned int u) {
    union { unsigned int i; float f; } c; c.i = u; return c.f;
}

// ---- fused prep: blocks <512 transpose x (NCHW fp32 -> NHWC bf16);
//      blocks >=512 cast+permute weight to [co][n*64+ci] bf16 ----
__global__ __launch_bounds__(256) void prep_fused(const float* __restrict__ x,
                                                  const float* __restrict__ w,
                                                  ushort* __restrict__ xt,
                                                  short* __restrict__ wt) {
    __shared__ float tile[64][65];
    const int t = threadIdx.x;
    if (blockIdx.x >= BB * HH) {                  // weight prep: 144 blocks
        int idx = (blockIdx.x - BB * HH) * 256 + t;   // co*576 + ci*9 + n
        if (idx < COUT * KTOT) {
            int co = idx / KTOT;
            int r  = idx - co * KTOT;
            int ci = r / N9;
            int n  = r - ci * N9;
            __hip_bfloat16 h = __float2bfloat16(w[idx]);
            wt[co * KTOT + n * CIN + ci] = *reinterpret_cast<short*>(&h);
        }
        return;
    }
    const int bh = blockIdx.x;                    // b*64 + h
    const int b = bh >> 6, h = bh & 63;
    const int r0 = t >> 6;                        // 0..3
    const int c  = t & 63;
    const float* xp = x + ((b * CIN) * HH + h) * WW;
    #pragma unroll
    for (int s = 0; s < 16; ++s) {
        const int ci = s * 4 + r0;
        tile[ci][c] = xp[ci * (HH * WW) + c];     // coalesced in w
    }
    __syncthreads();
    ushort* xo = xt + (b * HH + h) * (WW * CIN);
    #pragma unroll
    for (int s = 0; s < 16; ++s) {
        const int w2 = s * 4 + r0;
        __hip_bfloat16 hv = __float2bfloat16(tile[c][w2]);
        xo[w2 * CIN + c] = *reinterpret_cast<ushort*>(&hv); // coalesced in ci
    }
}

// ---- main kernel: one block = 32 output pixels, all 64 c_out ----
// wave role: (px-slice = wave&1, co-half = wave>>1); each wave: 1 B ds_read
// feeds 2 MFMAs (co-tiles +0,+16) -> block B-panel LDS reads cut 4x.
__global__ __launch_bounds__(256, 4) void deform_main(
    const ushort* __restrict__ xt,   // (8, 64, 64, 64) NHWC bf16
    const float* __restrict__ off,   // (8, 18, 64, 64)
    const short* __restrict__ wtb,   // (64, 576) bf16, k = n*64+ci
    float* __restrict__ out) {       // (8, 64, 64, 64)

    __shared__ unsigned int s_g01[NTASK];
    __shared__ unsigned int s_g23[NTASK];
    __shared__ int          s_bse[NTASK];
    __attribute__((aligned(16))) __shared__ short S[TPX][SROW];

    const int t    = threadIdx.x;
    const int lane = t & 63;
    const int wave = t >> 6;
    const int g8   = t & 7;          // ci octet (constant per thread)
    const int t8   = t >> 3;

    // XCD swizzle: each XCD (g&7) owns one full batch -> L2-resident working set
    const int logical = (blockIdx.x & 7) * 128 + (blockIdx.x >> 3);
    const int pix0 = logical * TPX;
    const int b    = pix0 >> 12;
    const int i    = (pix0 >> 6) & 63;
    const int j0   = pix0 & 63;          // 0 or 32

    const int lr  = lane & 15;       // A row within tile / B col within slice
    const int kq  = lane >> 4;       // k-octet selector
    const int pxr = (wave & 1) * 16 + lr;    // S row this wave's B-frag reads
    const int coh = (wave >> 1) * 32;        // co half base
    const short* arow0 = wtb + (coh + lr) * KTOT + kq * 8;
    const short* arow1 = arow0 + 16 * KTOT;
    const ushort* xb = xt + b * (HH * WW * CIN);

    // ---- phase 0: sampling geometry (288 tasks) ----
    for (int task = t; task < NTASK; task += 256) {
        const int n  = task >> 5;
        const int px = task & 31;
        const int j  = j0 + px;
        const float offx = off[(((b * 18) + 2 * n) * HH + i) * WW + j];
        const float offy = off[(((b * 18) + 2 * n + 1) * HH + i) * WW + j];
        const float pxf = (float)(i + n / 3) + offx;
        const float pyf = (float)(j + n % 3) + offy;
        const float fpx = floorf(pxf);
        const float fpy = floorf(pyf);
        const float qltx = fminf(fmaxf(fpx, 0.f), 65.f);
        const float qlty = fminf(fmaxf(fpy, 0.f), 65.f);
        const float qrbx = fminf(fmaxf(fpx + 1.f, 0.f), 65.f);
        const float qrby = fminf(fmaxf(fpy + 1.f, 0.f), 65.f);
        const bool mx = (pxf < 1.f) || (pxf > 64.f);
        const bool my = (pyf < 1.f) || (pyf > 64.f);
        const float Px = fminf(fmaxf(mx ? fpx : pxf, 0.f), 65.f);
        const float Py = fminf(fmaxf(my ? fpy : pyf, 0.f), 65.f);
        float ul = 1.f + (qltx - Px);
        float ur = 1.f - (qrbx - Px);
        float wl = 1.f + (qlty - Py);
        float wr = 1.f - (qrby - Py);
        const int ltx = (int)qltx, lty = (int)qlty;
        const int rbx = (int)qrbx, rby = (int)qrby;
        if (ltx < 1 || ltx > 64) ul = 0.f;
        if (rbx < 1 || rbx > 64) ur = 0.f;
        if (lty < 1 || lty > 64) wl = 0.f;
        if (rby < 1 || rby > 64) wr = 0.f;
        const int r = ltx - 1, c = lty - 1;
        const int rp = min(max(r, 0), 62), cp = min(max(c, 0), 62);
        const float u0 = (rp == r ? ul : 0.f) + (rp == rbx - 1 ? ur : 0.f);
        const float u1 = (rp + 1 == r ? ul : 0.f) + (rp + 1 == rbx - 1 ? ur : 0.f);
        const float w0 = (cp == c ? wl : 0.f) + (cp == rby - 1 ? wr : 0.f);
        const float w1 = (cp + 1 == c ? wl : 0.f) + (cp + 1 == rby - 1 ? wr : 0.f);
        __half2 h01 = __floats2half2_rn(u0 * w0, u0 * w1);
        __half2 h23 = __floats2half2_rn(u1 * w0, u1 * w1);
        s_g01[task] = *reinterpret_cast<unsigned int*>(&h01);
        s_g23[task] = *reinterpret_cast<unsigned int*>(&h23);
        s_bse[task] = (rp * WW + cp) * CIN;
    }

    f32x4 acc0 = {0.f, 0.f, 0.f, 0.f};
    f32x4 acc1 = {0.f, 0.f, 0.f, 0.f};

    #define GLOADS(G, u)                                                      \
        _Pragma("unroll")                                                     \
        for (int it = 0; it < 3; ++it) {                                      \
            const int task = 96 * (G) + 32 * it + t8;                         \
            const int bse  = s_bse[task] + g8 * 8;                            \
            u[0][it] = *(const uint32x4*)(xb + bse);                          \
            u[1][it] = *(const uint32x4*)(xb + bse + CIN);                    \
            u[2][it] = *(const uint32x4*)(xb + bse + WW * CIN);               \
            u[3][it] = *(const uint32x4*)(xb + bse + WW * CIN + CIN);         \
        }

    #define GBLEND(G, u)                                                      \
        _Pragma("unroll")                                                     \
        for (int it = 0; it < 3; ++it) {                                      \
            const int task = 96 * (G) + 32 * it + t8;                         \
            const float2 g01 = __half22float2(*reinterpret_cast<const __half2*>(&s_g01[task])); \
            const float2 g23 = __half22float2(*reinterpret_cast<const __half2*>(&s_g23[task])); \
            f32x2 f0 = {0.f, 0.f}, f1 = {0.f, 0.f}, f2 = {0.f, 0.f}, f3 = {0.f, 0.f}; \
            _Pragma("unroll")                                                 \
            for (int cc = 0; cc < 4; ++cc) {                                  \
                const uint32x4 uv = u[cc][it];                                \
                const float gc = (cc == 0) ? g01.x : (cc == 1) ? g01.y : (cc == 2) ? g23.x : g23.y; \
                f0 += gc * (f32x2){uasf(uv[0] << 16), uasf(uv[0] & 0xffff0000u)}; \
                f1 += gc * (f32x2){uasf(uv[1] << 16), uasf(uv[1] & 0xffff0000u)}; \
                f2 += gc * (f32x2){uasf(uv[2] << 16), uasf(uv[2] & 0xffff0000u)}; \
                f3 += gc * (f32x2){uasf(uv[3] << 16), uasf(uv[3] & 0xffff0000u)}; \
            }                                                                 \
            bf16x8 sv;                                                        \
            { __hip_bfloat16 h;                                               \
              h = __float2bfloat16(f0.x); sv[0] = *reinterpret_cast<short*>(&h); \
              h = __float2bfloat16(f0.y); sv[1] = *reinterpret_cast<short*>(&h); \
              h = __float2bfloat16(f1.x); sv[2] = *reinterpret_cast<short*>(&h); \
              h = __float2bfloat16(f1.y); sv[3] = *reinterpret_cast<short*>(&h); \
              h = __float2bfloat16(f2.x); sv[4] = *reinterpret_cast<short*>(&h); \
              h = __float2bfloat16(f2.y); sv[5] = *reinterpret_cast<short*>(&h); \
              h = __float2bfloat16(f3.x); sv[6] = *reinterpret_cast<short*>(&h); \
              h = __float2bfloat16(f3.y); sv[7] = *reinterpret_cast<short*>(&h); } \
            const int px = task & 31;                                         \
            const int n  = task >> 5;                                         \
            *reinterpret_cast<bf16x8*>(&S[px][n * CIN + g8 * 8]) = sv;        \
        }

    // region-G A-fragment loads (issued FIRST in a stage -> oldest vmem)
    #define LOADAF(G, af0, af1)                                               \
        _Pragma("unroll")                                                     \
        for (int k6 = 0; k6 < 6; ++k6) {                                      \
            af0[k6] = *reinterpret_cast<const bf16x8*>(arow0 + ((G) * 6 + k6) * 32); \
            af1[k6] = *reinterpret_cast<const bf16x8*>(arow1 + ((G) * 6 + k6) * 32); \
        }

    // region-G MFMAs: 6 k-steps, 1 B ds_read feeds 2 co-tiles
    #define MFMAR(G, af0, af1)                                                \
        _Pragma("unroll")                                                     \
        for (int k6 = 0; k6 < 6; ++k6) {                                      \
            bf16x8 bv = *reinterpret_cast<const bf16x8*>(&S[pxr][((G) * 6 + k6) * 32 + kq * 8]); \
            acc0 = __builtin_amdgcn_mfma_f32_16x16x32_bf16(af0[k6], bv, acc0, 0, 0, 0); \
            acc1 = __builtin_amdgcn_mfma_f32_16x16x32_bf16(af1[k6], bv, acc1, 0, 0, 0); \
        }

    __syncthreads();

    // ---- prologue: gather region 0 ----
    {
        uint32x4 u[4][3];
        GLOADS(0, u)
        GBLEND(0, u)
    }
    __syncthreads();

    // ---- stage 0 ----
    {
        bf16x8 af0[6], af1[6];
        LOADAF(0, af0, af1)
        uint32x4 u[4][3];
        GLOADS(1, u)
        MFMAR(0, af0, af1)
        GBLEND(1, u)
    }
    __syncthreads();

    // ---- stage 1 ----
    {
        bf16x8 af0[6], af1[6];
        LOADAF(1, af0, af1)
        uint32x4 u[4][3];
        GLOADS(2, u)
        MFMAR(1, af0, af1)
        GBLEND(2, u)
    }
    __syncthreads();

    // ---- stage 2 ----
    {
        bf16x8 af0[6], af1[6];
        LOADAF(2, af0, af1)
        MFMAR(2, af0, af1)
    }

    // ---- epilogue ----
    #pragma unroll
    for (int v = 0; v < 4; ++v) {
        const int co = coh + kq * 4 + v;         // D row = (lane>>4)*4 + v
        float* op = out + ((b * COUT + co) * HH + i) * WW + j0 + (wave & 1) * 16;
        op[lr]                = acc0[v];
        op[16 * HH * WW - (wave & 1) * 16 + (wave & 1) * 16 + lr] = acc1[v];
    }
}

extern "C" void kernel_launch(void* const* d_in, const int* in_sizes, int n_in,
                              void* d_out, int out_size, void* d_ws, size_t ws_size,
                              hipStream_t stream) {
    const float* x   = (const float*)d_in[0];
    const float* off = (const float*)d_in[1];
    const float* w   = (const float*)d_in[2];
    float* out = (float*)d_out;
    short* wtb  = (short*)d_ws;                      // 73728 B
    ushort* xt  = (ushort*)((char*)d_ws + 131072);   // 4.2 MB NHWC bf16 copy

    const int prep_blocks = BB * HH + (COUT * KTOT + 255) / 256;  // 512 + 144
    hipLaunchKernelGGL(prep_fused, dim3(prep_blocks), dim3(256), 0, stream,
                       x, w, xt, wtb);
    hipLaunchKernelGGL(deform_main, dim3(BB * HH * WW / TPX), dim3(256), 0, stream,
                       xt, off, wtb, out);
}

// Round 10
// 25.749 us; speedup vs baseline: 1.2904x; 1.2904x over previous
//
#include <hip/hip_runtime.h>
#include <hip/hip_bf16.h>
#include <hip/hip_fp16.h>

#define N9 9
#define TPX 32          // pixels per block (contiguous j within one row)
#define CIN 64
#define COUT 64
#define HH 64
#define WW 64
#define BB 8
#define KTOT 576        // 9 points * 64 ci, k = n*64 + ci
#define SROW 584        // padded LDS row stride in shorts (1168 B = 73*16)
#define NTASK (N9 * TPX)

typedef short bf16x8 __attribute__((ext_vector_type(8)));
typedef float f32x4 __attribute__((ext_vector_type(4)));
typedef float f32x2 __attribute__((ext_vector_type(2)));
typedef unsigned int uint32x4 __attribute__((ext_vector_type(4)));

__device__ __forceinline__ float uasf(unsigned int u) {
    union { unsigned int i; float f; } c; c.i = u; return c.f;
}

// ---- fused prep: blocks <512 transpose x (NCHW fp32 -> NHWC bf16);
//      blocks >=512 cast+permute weight to [co][n*64+ci] bf16 ----
__global__ __launch_bounds__(256) void prep_fused(const float* __restrict__ x,
                                                  const float* __restrict__ w,
                                                  ushort* __restrict__ xt,
                                                  short* __restrict__ wt) {
    __shared__ float tile[64][65];
    const int t = threadIdx.x;
    if (blockIdx.x >= BB * HH) {                  // weight prep: 144 blocks
        int idx = (blockIdx.x - BB * HH) * 256 + t;   // co*576 + ci*9 + n
        if (idx < COUT * KTOT) {
            int co = idx / KTOT;
            int r  = idx - co * KTOT;
            int ci = r / N9;
            int n  = r - ci * N9;
            __hip_bfloat16 h = __float2bfloat16(w[idx]);
            wt[co * KTOT + n * CIN + ci] = *reinterpret_cast<short*>(&h);
        }
        return;
    }
    const int bh = blockIdx.x;                    // b*64 + h
    const int b = bh >> 6, h = bh & 63;
    const int r0 = t >> 6;                        // 0..3
    const int c  = t & 63;
    const float* xp = x + ((b * CIN) * HH + h) * WW;
    #pragma unroll
    for (int s = 0; s < 16; ++s) {
        const int ci = s * 4 + r0;
        tile[ci][c] = xp[ci * (HH * WW) + c];     // coalesced in w
    }
    __syncthreads();
    ushort* xo = xt + (b * HH + h) * (WW * CIN);
    #pragma unroll
    for (int s = 0; s < 16; ++s) {
        const int w2 = s * 4 + r0;
        __hip_bfloat16 hv = __float2bfloat16(tile[c][w2]);
        xo[w2 * CIN + c] = *reinterpret_cast<ushort*>(&hv); // coalesced in ci
    }
}

// ---- main kernel: one block = 32 output pixels, all 64 c_out ----
// R8 structure (3-region K-pipeline); LDS dieted to 40,256 B via ushort
// patch-index -> 4 blocks/CU residency.
__global__ __launch_bounds__(256, 4) void deform_main(
    const ushort* __restrict__ xt,   // (8, 64, 64, 64) NHWC bf16
    const float* __restrict__ off,   // (8, 18, 64, 64)
    const short* __restrict__ wtb,   // (64, 576) bf16, k = n*64+ci
    float* __restrict__ out) {       // (8, 64, 64, 64)

    __shared__ unsigned int s_g01[NTASK];
    __shared__ unsigned int s_g23[NTASK];
    __shared__ ushort       s_bse[NTASK];   // patch base / 64 (rp*WW+cp <= 4030)
    __attribute__((aligned(16))) __shared__ short S[TPX][SROW];

    const int t    = threadIdx.x;
    const int lane = t & 63;
    const int wave = t >> 6;
    const int g8   = t & 7;          // ci octet (constant per thread)
    const int t8   = t >> 3;

    // XCD swizzle: each XCD (g&7) owns one full batch -> L2-resident working set
    const int logical = (blockIdx.x & 7) * 128 + (blockIdx.x >> 3);
    const int pix0 = logical * TPX;
    const int b    = pix0 >> 12;
    const int i    = (pix0 >> 6) & 63;
    const int j0   = pix0 & 63;          // 0 or 32

    const int lr = lane & 15;        // A row (co) / B col (px)
    const int kq = lane >> 4;        // k-octet selector
    const short* arow = wtb + (wave * 16 + lr) * KTOT + kq * 8;
    const ushort* xb = xt + b * (HH * WW * CIN);

    // ---- phase 0: sampling geometry (288 tasks) ----
    for (int task = t; task < NTASK; task += 256) {
        const int n  = task >> 5;
        const int px = task & 31;
        const int j  = j0 + px;
        const float offx = off[(((b * 18) + 2 * n) * HH + i) * WW + j];
        const float offy = off[(((b * 18) + 2 * n + 1) * HH + i) * WW + j];
        const float pxf = (float)(i + n / 3) + offx;
        const float pyf = (float)(j + n % 3) + offy;
        const float fpx = floorf(pxf);
        const float fpy = floorf(pyf);
        const float qltx = fminf(fmaxf(fpx, 0.f), 65.f);
        const float qlty = fminf(fmaxf(fpy, 0.f), 65.f);
        const float qrbx = fminf(fmaxf(fpx + 1.f, 0.f), 65.f);
        const float qrby = fminf(fmaxf(fpy + 1.f, 0.f), 65.f);
        const bool mx = (pxf < 1.f) || (pxf > 64.f);
        const bool my = (pyf < 1.f) || (pyf > 64.f);
        const float Px = fminf(fmaxf(mx ? fpx : pxf, 0.f), 65.f);
        const float Py = fminf(fmaxf(my ? fpy : pyf, 0.f), 65.f);
        float ul = 1.f + (qltx - Px);
        float ur = 1.f - (qrbx - Px);
        float wl = 1.f + (qlty - Py);
        float wr = 1.f - (qrby - Py);
        const int ltx = (int)qltx, lty = (int)qlty;
        const int rbx = (int)qrbx, rby = (int)qrby;
        if (ltx < 1 || ltx > 64) ul = 0.f;
        if (rbx < 1 || rbx > 64) ur = 0.f;
        if (lty < 1 || lty > 64) wl = 0.f;
        if (rby < 1 || rby > 64) wr = 0.f;
        const int r = ltx - 1, c = lty - 1;
        const int rp = min(max(r, 0), 62), cp = min(max(c, 0), 62);
        const float u0 = (rp == r ? ul : 0.f) + (rp == rbx - 1 ? ur : 0.f);
        const float u1 = (rp + 1 == r ? ul : 0.f) + (rp + 1 == rbx - 1 ? ur : 0.f);
        const float w0 = (cp == c ? wl : 0.f) + (cp == rby - 1 ? wr : 0.f);
        const float w1 = (cp + 1 == c ? wl : 0.f) + (cp + 1 == rby - 1 ? wr : 0.f);
        __half2 h01 = __floats2half2_rn(u0 * w0, u0 * w1);
        __half2 h23 = __floats2half2_rn(u1 * w0, u1 * w1);
        s_g01[task] = *reinterpret_cast<unsigned int*>(&h01);
        s_g23[task] = *reinterpret_cast<unsigned int*>(&h23);
        s_bse[task] = (ushort)(rp * WW + cp);
    }

    f32x4 acc0 = {0.f, 0.f, 0.f, 0.f};
    f32x4 acc1 = {0.f, 0.f, 0.f, 0.f};

    #define GLOADS(G, u)                                                      \
        _Pragma("unroll")                                                     \
        for (int it = 0; it < 3; ++it) {                                      \
            const int task = 96 * (G) + 32 * it + t8;                         \
            const int bse  = (int)s_bse[task] * CIN + g8 * 8;                 \
            u[0][it] = *(const uint32x4*)(xb + bse);                          \
            u[1][it] = *(const uint32x4*)(xb + bse + CIN);                    \
            u[2][it] = *(const uint32x4*)(xb + bse + WW * CIN);               \
            u[3][it] = *(const uint32x4*)(xb + bse + WW * CIN + CIN);         \
        }

    #define GBLEND(G, u)                                                      \
        _Pragma("unroll")                                                     \
        for (int it = 0; it < 3; ++it) {                                      \
            const int task = 96 * (G) + 32 * it + t8;                         \
            const float2 g01 = __half22float2(*reinterpret_cast<const __half2*>(&s_g01[task])); \
            const float2 g23 = __half22float2(*reinterpret_cast<const __half2*>(&s_g23[task])); \
            f32x2 f0 = {0.f, 0.f}, f1 = {0.f, 0.f}, f2 = {0.f, 0.f}, f3 = {0.f, 0.f}; \
            _Pragma("unroll")                                                 \
            for (int cc = 0; cc < 4; ++cc) {                                  \
                const uint32x4 uv = u[cc][it];                                \
                const float gc = (cc == 0) ? g01.x : (cc == 1) ? g01.y : (cc == 2) ? g23.x : g23.y; \
                f0 += gc * (f32x2){uasf(uv[0] << 16), uasf(uv[0] & 0xffff0000u)}; \
                f1 += gc * (f32x2){uasf(uv[1] << 16), uasf(uv[1] & 0xffff0000u)}; \
                f2 += gc * (f32x2){uasf(uv[2] << 16), uasf(uv[2] & 0xffff0000u)}; \
                f3 += gc * (f32x2){uasf(uv[3] << 16), uasf(uv[3] & 0xffff0000u)}; \
            }                                                                 \
            bf16x8 sv;                                                        \
            { __hip_bfloat16 h;                                               \
              h = __float2bfloat16(f0.x); sv[0] = *reinterpret_cast<short*>(&h); \
              h = __float2bfloat16(f0.y); sv[1] = *reinterpret_cast<short*>(&h); \
              h = __float2bfloat16(f1.x); sv[2] = *reinterpret_cast<short*>(&h); \
              h = __float2bfloat16(f1.y); sv[3] = *reinterpret_cast<short*>(&h); \
              h = __float2bfloat16(f2.x); sv[4] = *reinterpret_cast<short*>(&h); \
              h = __float2bfloat16(f2.y); sv[5] = *reinterpret_cast<short*>(&h); \
              h = __float2bfloat16(f3.x); sv[6] = *reinterpret_cast<short*>(&h); \
              h = __float2bfloat16(f3.y); sv[7] = *reinterpret_cast<short*>(&h); } \
            const int px = task & 31;                                         \
            const int n  = task >> 5;                                         \
            *reinterpret_cast<bf16x8*>(&S[px][n * CIN + g8 * 8]) = sv;        \
        }

    // region-G A-fragment load (issued FIRST in a stage -> oldest vmem)
    #define LOADAF(G, af)                                                     \
        _Pragma("unroll")                                                     \
        for (int k6 = 0; k6 < 6; ++k6)                                        \
            af[k6] = *reinterpret_cast<const bf16x8*>(arow + ((G) * 6 + k6) * 32);

    // region-G MFMAs (12)
    #define MFMAR(G, af)                                                      \
        _Pragma("unroll")                                                     \
        for (int k6 = 0; k6 < 6; ++k6) {                                      \
            bf16x8 b0 = *reinterpret_cast<const bf16x8*>(&S[lr][((G) * 6 + k6) * 32 + kq * 8]);      \
            bf16x8 b1 = *reinterpret_cast<const bf16x8*>(&S[lr + 16][((G) * 6 + k6) * 32 + kq * 8]); \
            acc0 = __builtin_amdgcn_mfma_f32_16x16x32_bf16(af[k6], b0, acc0, 0, 0, 0); \
            acc1 = __builtin_amdgcn_mfma_f32_16x16x32_bf16(af[k6], b1, acc1, 0, 0, 0); \
        }

    __syncthreads();

    // ---- prologue: gather region 0 ----
    {
        uint32x4 u[4][3];
        GLOADS(0, u)
        GBLEND(0, u)
    }
    __syncthreads();

    // ---- stage 0: load af0, issue gather(1), MFMA region 0, blend(1) ----
    {
        bf16x8 af[6];
        LOADAF(0, af)
        uint32x4 u[4][3];
        GLOADS(1, u)
        MFMAR(0, af)
        GBLEND(1, u)
    }
    __syncthreads();

    // ---- stage 1: load af1, issue gather(2), MFMA region 1, blend(2) ----
    {
        bf16x8 af[6];
        LOADAF(1, af)
        uint32x4 u[4][3];
        GLOADS(2, u)
        MFMAR(1, af)
        GBLEND(2, u)
    }
    __syncthreads();

    // ---- stage 2: MFMA region 2 ----
    {
        bf16x8 af[6];
        LOADAF(2, af)
        MFMAR(2, af)
    }

    // ---- epilogue ----
    #pragma unroll
    for (int v = 0; v < 4; ++v) {
        const int co = wave * 16 + kq * 4 + v;   // D row = (lane>>4)*4 + v
        float* op = out + ((b * COUT + co) * HH + i) * WW + j0;
        op[lr]      = acc0[v];
        op[16 + lr] = acc1[v];
    }
}

extern "C" void kernel_launch(void* const* d_in, const int* in_sizes, int n_in,
                              void* d_out, int out_size, void* d_ws, size_t ws_size,
                              hipStream_t stream) {
    const float* x   = (const float*)d_in[0];
    const float* off = (const float*)d_in[1];
    const float* w   = (const float*)d_in[2];
    float* out = (float*)d_out;
    short* wtb  = (short*)d_ws;                      // 73728 B
    ushort* xt  = (ushort*)((char*)d_ws + 131072);   // 4.2 MB NHWC bf16 copy

    const int prep_blocks = BB * HH + (COUT * KTOT + 255) / 256;  // 512 + 144
    hipLaunchKernelGGL(prep_fused, dim3(prep_blocks), dim3(256), 0, stream,
                       x, w, xt, wtb);
    hipLaunchKernelGGL(deform_main, dim3(BB * HH * WW / TPX), dim3(256), 0, stream,
                       xt, off, wtb, out);
}